// Round 4
// baseline (121.885 us; speedup 1.0000x reference)
//
#include <hip/hip_runtime.h>
#include <cstddef>

#define EPS 1e-5f

constexpr int NG  = 8192;   // genes
constexpr int HID = 32768;  // hidden (= NG*4)
constexpr int NTF = 1024;   // TFs
constexpr int B   = 256;    // batch

// round-to-nearest-even f32 -> bf16 bits (no NaN inputs in this problem)
static __device__ __forceinline__ unsigned short f2bf(float v) {
    union { float f; unsigned u; } a; a.f = v;
    unsigned r = a.u + 0x7fffu + ((a.u >> 16) & 1u);
    return (unsigned short)(r >> 16);
}

// ---------------------------------------------------------------------------
// Kernel 1: fused  sparse-L1 -> relu -> BN1 -> sparse-L2(4x4 blockdiag) -> relu
// Writes relu(h2) TRANSPOSED [HID][B] in bf16 (coalesced gather for layer 3),
// plus per-column invstd2 so BN2 folds into layer-3 weights. (BN2 mean and b3
// cancel under BN3's mean subtraction, so they are not stored at all.)
//
// Block = 256 threads = 64 columns x 4 batch-slices of 64. BN1/BN2 stats are
// gene-local, so everything stays inside the block.
// ---------------------------------------------------------------------------
__global__ __launch_bounds__(256) void fused12(
    const float* __restrict__ x,       // [B][NG]
    const float* __restrict__ w1,      // [HID]
    const float* __restrict__ b1,      // [HID]
    const float* __restrict__ w2,      // [HID*4]
    const float* __restrict__ b2,      // [HID]
    unsigned short* __restrict__ h2rT, // [HID][B] bf16 bits
    float* __restrict__ inv2g)         // [HID]
{
    const int lane  = threadIdx.x & 63;   // column within block tile
    const int slice = threadIdx.x >> 6;   // which 64-row batch slice
    const int c     = (blockIdx.x << 6) + lane;  // global hidden column
    const int g     = c >> 2;             // gene
    const int b0    = slice << 6;

    __shared__ float redA[4][64], redB[4][64];
    __shared__ float m1s[64], inv1s[64];

    const float w1c = w1[c], b1c = b1[c];
    const float* xp = x + (size_t)b0 * NG + g;

    // ---- phase A: BN1 stats for column c over this thread's 64 rows ----
    float s = 0.f, s2 = 0.f;
    #pragma unroll 8
    for (int i = 0; i < 64; ++i) {
        float h = fmaxf(fmaf(w1c, xp[(size_t)i * NG], b1c), 0.f);
        s += h;
        s2 = fmaf(h, h, s2);
    }
    redA[slice][lane] = s;
    redB[slice][lane] = s2;
    __syncthreads();
    if (slice == 0) {
        float S  = redA[0][lane] + redA[1][lane] + redA[2][lane] + redA[3][lane];
        float S2 = redB[0][lane] + redB[1][lane] + redB[2][lane] + redB[3][lane];
        float m  = S * (1.f / 256.f);
        float v  = fmaf(-m, m, S2 * (1.f / 256.f));
        m1s[lane]   = m;
        inv1s[lane] = rsqrtf(v + EPS);
    }
    __syncthreads();

    // ---- fold BN1 into the 4x4 block weights ----
    const int lbase = lane & ~3;   // first column of my gene in LDS tile
    const int gbase = g << 2;      // first global column of my gene
    float w1j[4], b1j[4], w2s[4];
    float bconst = b2[c];
    #pragma unroll
    for (int j = 0; j < 4; ++j) {
        w1j[j] = w1[gbase + j];
        b1j[j] = b1[gbase + j];
        float wv = w2[(c << 2) + j] * inv1s[lbase + j];
        w2s[j] = wv;
        bconst = fmaf(-wv, m1s[lbase + j], bconst);
    }

    // ---- phase B: recompute h1, folded L2, relu, BN2 stats, bf16 store ----
    float t2s = 0.f, t2s2 = 0.f;
    unsigned short* op = h2rT + (size_t)c * B + b0;
    for (int i0 = 0; i0 < 64; i0 += 4) {
        ushort4 pk;
        unsigned short* pp = (unsigned short*)&pk;
        #pragma unroll
        for (int u = 0; u < 4; ++u) {
            float v = xp[(size_t)(i0 + u) * NG];
            float acc = bconst;
            #pragma unroll
            for (int j = 0; j < 4; ++j) {
                float r = fmaxf(fmaf(w1j[j], v, b1j[j]), 0.f);
                acc = fmaf(w2s[j], r, acc);
            }
            float r2 = fmaxf(acc, 0.f);
            t2s += r2;
            t2s2 = fmaf(r2, r2, t2s2);
            pp[u] = f2bf(r2);
        }
        *(ushort4*)(op + i0) = pk;   // 8 B store, aligned
    }

    __syncthreads();                 // phase-A reads of redA/redB done
    redA[slice][lane] = t2s;
    redB[slice][lane] = t2s2;
    __syncthreads();
    if (slice == 0) {
        float S  = redA[0][lane] + redA[1][lane] + redA[2][lane] + redA[3][lane];
        float S2 = redB[0][lane] + redB[1][lane] + redB[2][lane] + redB[3][lane];
        float m  = S * (1.f / 256.f);
        float v  = fmaf(-m, m, S2 * (1.f / 256.f));
        inv2g[c] = rsqrtf(v + EPS);
    }
}

// ---------------------------------------------------------------------------
// Prep: fold BN2 invstd into layer-3 weights; precompute column byte offsets.
// ---------------------------------------------------------------------------
__global__ __launch_bounds__(256) void prep3(
    const float* __restrict__ w3,     // [NTF*256]
    const int*   __restrict__ cols3,  // [NTF*256]
    const float* __restrict__ inv2g,  // [HID]
    float* __restrict__ wfold,        // [NTF*256]
    int*   __restrict__ colb)         // [NTF*256] byte offsets
{
    const int i = (blockIdx.x << 8) + threadIdx.x;
    const int col = cols3[i];
    wfold[i] = w3[i] * inv2g[col];
    colb[i]  = col << 9;              // col * B * sizeof(bf16)
}

// ---------------------------------------------------------------------------
// Gather-dot, XCD-sliced: block = (TF t, 32-row batch slice).
// slice = blockIdx & 7  ->  all blocks of one slice land on one XCD
// (round-robin dispatch heuristic), so the slice's [HID][32] = 2.1 MB chunk
// of h2rT stays resident in that XCD's 4 MB L2 across all 1024 TFs.
// Thread = (edge-group eg of 16, row-pair r2 of 16); one uint load = 2 rows.
// Per wave-load: 4 columns x 64 B contiguous segments.
// ---------------------------------------------------------------------------
__global__ __launch_bounds__(256) void gather3(
    const unsigned short* __restrict__ h2,  // [HID][B] bf16 bits
    const float* __restrict__ wfold,        // [NTF*256]
    const int*   __restrict__ colb,         // [NTF*256]
    float* __restrict__ zraw)               // [NTF][B]
{
    const int slice = blockIdx.x & 7;
    const int t     = blockIdx.x >> 3;
    const int tid   = threadIdx.x;

    __shared__ float wls[256];
    __shared__ int   alds[256];
    __shared__ float sred[16][33];   // +1 pad: kills bank conflicts

    wls[tid]  = wfold[(t << 8) + tid];
    alds[tid] = colb[(t << 8) + tid];
    __syncthreads();

    const int eg = tid >> 4;               // 16 edge groups
    const int r2 = tid & 15;               // row-pair within slice
    const int boff = (slice << 6) + (r2 << 2);  // byte offset inside column
    const char* h2c = (const char*)h2;

    float a0 = 0.f, a1 = 0.f;
    #pragma unroll
    for (int k = 0; k < 16; ++k) {
        const int e = (k << 4) | eg;
        float w = wls[e];
        unsigned u = *(const unsigned*)(h2c + alds[e] + boff);  // rows 2r2,2r2+1
        union { unsigned v; float f; } lo, hi;
        lo.v = u << 16;
        hi.v = u & 0xffff0000u;
        a0 = fmaf(w, lo.f, a0);
        a1 = fmaf(w, hi.f, a1);
    }
    sred[eg][(r2 << 1)]     = a0;
    sred[eg][(r2 << 1) + 1] = a1;
    __syncthreads();

    if (tid < 32) {
        float s = 0.f;
        #pragma unroll
        for (int e = 0; e < 16; ++e) s += sred[e][tid];
        zraw[(t << 8) + (slice << 5) + tid] = s;
    }
}

// ---------------------------------------------------------------------------
// BN3 over the batch for each TF. Per-t constants (b3, BN2-mean correction)
// cancel under the mean subtraction, so zraw needs no bias at all.
// ---------------------------------------------------------------------------
__global__ __launch_bounds__(256) void bn3(
    const float* __restrict__ zraw,   // [NTF][B]
    float* __restrict__ out)          // [B][NTF]
{
    const int t   = blockIdx.x;
    const int tid = threadIdx.x;      // batch row
    __shared__ float rs[4], rs2[4];

    float z = zraw[(t << 8) + tid];
    float s = z, s2 = z * z;
    #pragma unroll
    for (int o = 32; o > 0; o >>= 1) {
        s  += __shfl_xor(s, o);
        s2 += __shfl_xor(s2, o);
    }
    if ((tid & 63) == 0) { rs[tid >> 6] = s; rs2[tid >> 6] = s2; }
    __syncthreads();
    float S  = rs[0] + rs[1] + rs[2] + rs[3];
    float S2 = rs2[0] + rs2[1] + rs2[2] + rs2[3];
    float m  = S * (1.f / 256.f);
    float v  = fmaf(-m, m, S2 * (1.f / 256.f));
    out[(size_t)tid * NTF + t] = (z - m) * rsqrtf(v + EPS);
}

// ---------------------------------------------------------------------------
extern "C" void kernel_launch(void* const* d_in, const int* in_sizes, int n_in,
                              void* d_out, int out_size, void* d_ws, size_t ws_size,
                              hipStream_t stream) {
    const float* x   = (const float*)d_in[0];
    const float* w1  = (const float*)d_in[1];
    const float* b1  = (const float*)d_in[2];
    const float* w2  = (const float*)d_in[3];
    const float* b2  = (const float*)d_in[4];
    const float* w3  = (const float*)d_in[5];
    const float* b3  = (const float*)d_in[6];  (void)b3;  // cancels in BN3
    const int* cols3 = (const int*)d_in[12];
    float* out = (float*)d_out;

    // workspace layout
    unsigned short* h2rT = (unsigned short*)d_ws;                 // 16.8 MB
    float* inv2g = (float*)(h2rT + (size_t)HID * B);              // 128 KB
    float* wfold = inv2g + HID;                                   // 1 MB
    int*   colb  = (int*)(wfold + NTF * 256);                     // 1 MB
    float* zraw  = (float*)(colb + NTF * 256);                    // 1 MB

    fused12<<<HID / 64, 256, 0, stream>>>(x, w1, b1, w2, b2, h2rT, inv2g);
    prep3  <<<NTF,      256, 0, stream>>>(w3, cols3, inv2g, wfold, colb);
    gather3<<<NTF * 8,  256, 0, stream>>>(h2rT, wfold, colb, zraw);
    bn3    <<<NTF,      256, 0, stream>>>(zraw, out);
}